// Round 5
// baseline (5434.624 us; speedup 1.0000x reference)
//
#include <hip/hip_runtime.h>

// TimeLSTM persistent-scan kernel for MI355X (gfx950), round 8.
// Grid: 128 blocks x 320 threads (round-3 topology — best measured compute
// structure). grp = blockIdx&3 owns batches grp*16..+15; member = blockIdx>>2
// owns columns member*16..+15 of each gate and of W_d. Weights in VGPRs.
//
// Round-8 protocol: ACK-AS-READY. Round 3's chain was drain(RT) -> global
// flag + poll-detect(~1.5RT) -> gather(RT). The flag only encodes "producer
// stores ack'd", which each block learns LOCALLY from its own per-wave
// s_waitcnt vmcnt(0). Blocks are symmetric: when my publish is ack'd (~1 RT),
// every remote block's publish has already LANDED at MALL (~0.7 RT), so a
// gather issued now arrives fresh with ~0.5 RT margin. So:
//   EW -> tagged publish (qword {t+1 | f16 c,h}) -> own-slice LDS writes ->
//   wave-local vmcnt(0) -> LDS done-flag -> (out stores, x loads issue) ->
//   intra-block done poll (~50cy) -> single-shot gather -> sparse retry.
// vs rounds 4/6 (which stormed): gather CANNOT issue before stores are
// ack'd, so loads never interleave with in-flight publishes, and the delay
// self-calibrates with fabric congestion. Tag check (== t+1) + per-qword
// predicated retry is the correctness net for straggler blocks; 2-phase
// buffer bounds skew to 1 step; poison 0xAA.. never matches a tag <= 1024,
// so no workspace memset. Saves ~1.5 RT/step + one barrier/step.

typedef _Float16 f16;
typedef _Float16 f16x8 __attribute__((ext_vector_type(8)));
typedef float f32x4 __attribute__((ext_vector_type(4)));

#define S_ 1024
#define IN_ 256
#define H_ 512
#define ECONST 2.718281828459045f

__device__ __forceinline__ float sigf(float x) { return 1.0f / (1.0f + __expf(-x)); }
__device__ __forceinline__ float tanh_f(float x) { return 1.0f - 2.0f / (__expf(2.0f * x) + 1.0f); }

__device__ __forceinline__ unsigned long long pack_tagged(float h, float c, unsigned int tag) {
    union { f16 f; unsigned short u; } ph, pc;
    ph.f = (f16)h; pc.f = (f16)c;
    return ((unsigned long long)tag << 32) |
           ((unsigned long long)pc.u << 16) | (unsigned long long)ph.u;
}

__launch_bounds__(320, 2)
__global__ void tlstm_scan(
    const float* __restrict__ inputs, const float* __restrict__ tstamps,
    const int* __restrict__ lens,
    const float* __restrict__ W_all, const float* __restrict__ b_all,
    const float* __restrict__ U_all, const float* __restrict__ b_u,
    const float* __restrict__ W_d, const float* __restrict__ b_d,
    float* __restrict__ out0, float* __restrict__ out1, float* __restrict__ out2,
    unsigned long long* __restrict__ hcbuf)
{
    __shared__ __align__(16) f16 A_sm[96 * 16 * 8];   // 24 KB  (h: kb0..63, x: kb64..95)
    __shared__ __align__(16) f16 C_sm[64 * 16 * 8];   // 16 KB  (c operand)
    __shared__ float outs_sm[5 * 16 * 17];            // +1 pad on col
    __shared__ float c_loc[16 * 16];                  // fp32 c state (own cells)
    __shared__ float bias_sm[5 * 16];
    __shared__ int   len_sm[16];
    __shared__ unsigned int done_sm[4];               // per-EW-wave ack flags

    const int tid    = threadIdx.x;
    const int grp    = blockIdx.x & 3;
    const int member = blockIdx.x >> 2;
    const int wave   = tid >> 6;
    const int lane   = tid & 63;
    const int q      = lane >> 4;   // quad
    const int r16    = lane & 15;   // A: m / B: n / C: col
    const int j0     = member * 16;

    // ---------- preload weights into VGPRs as B-fragments ----------
    // B[k][n]: n = lane&15, k = kk*32 + q*8 + e
    f16x8 bw[24];
    if (wave < 4) {
        const int col = wave * 512 + j0 + r16;
#pragma unroll
        for (int kk = 0; kk < 24; ++kk) {
            f16x8 v;
            const int kbase = kk * 32 + q * 8;
#pragma unroll
            for (int e = 0; e < 8; ++e) {
                const int k = kbase + e;
                const float w = (kk < 16) ? W_all[k * 2048 + col]
                                          : U_all[(k - 512) * 2048 + col];
                v[e] = (f16)w;
            }
            bw[kk] = v;
        }
    } else {
        const int col = j0 + r16;
#pragma unroll
        for (int kk = 0; kk < 16; ++kk) {
            f16x8 v;
            const int kbase = kk * 32 + q * 8;
#pragma unroll
            for (int e = 0; e < 8; ++e) v[e] = (f16)W_d[(kbase + e) * 512 + col];
            bw[kk] = v;
        }
#pragma unroll
        for (int kk = 16; kk < 24; ++kk) bw[kk] = bw[0];
    }

    // slice list for this wave (6-7 remote slices, round-robin over 5 waves)
    int sl[7];
    int ns = 0;
    for (int s = wave; s < 32; s += 5)
        if (s != member) sl[ns++] = s;

    // ---------- init LDS state ----------
    {
        uint4 z; z.x = z.y = z.z = z.w = 0u;
        uint4* a4 = (uint4*)A_sm;
        uint4* c4 = (uint4*)C_sm;
        for (int i = tid; i < 1024; i += 320) { a4[i] = z; c4[i] = z; }
        if (tid < 256) c_loc[tid] = 0.0f;
        if (tid < 4) done_sm[tid] = 0u;
        if (tid < 64) {
            const int w = tid >> 4, n = tid & 15;
            const int col = w * 512 + j0 + n;
            bias_sm[w * 16 + n] = b_all[col] + b_u[col];
        } else if (tid < 80) {
            const int n = tid & 15;
            bias_sm[64 + n] = b_d[j0 + n];
        }
        if (tid < 16) len_sm[tid] = lens[grp * 16 + tid];
        // stage x(0) into A_sm kb 64..95
        for (int idx = tid; idx < 1024; idx += 320) {
            const int b = idx >> 6;
            const int kx0 = (idx & 63) << 2;
            const float4 v = *(const float4*)&inputs[(((size_t)(grp * 16 + b)) * S_ + 0) * IN_ + kx0];
            union { f16 h[4]; uint2 u; } p;
            p.h[0] = (f16)v.x; p.h[1] = (f16)v.y; p.h[2] = (f16)v.z; p.h[3] = (f16)v.w;
            const int kb = 64 + (kx0 >> 3), e = kx0 & 7;
            *(uint2*)&A_sm[(kb * 16 + b) * 8 + e] = p.u;
        }
    }
    __syncthreads();

    // per-group exchange buffer: 2 phases x 8192 qwords (64 KB per phase)
    unsigned long long* const hc_g = hcbuf + (size_t)grp * 2 * 8192;

    for (int t = 0; t < S_; ++t) {
        // ts(t) prefetch — overlaps the MFMA phase below
        float ts = 0.0f;
        if (tid < 256) {
            const int gb = grp * 16 + (tid >> 4);
            ts = tstamps[(size_t)gb * S_ + t];
        }

        // ---------- MFMA phase ----------
        f32x4 acc0 = {0.f, 0.f, 0.f, 0.f}, acc1 = {0.f, 0.f, 0.f, 0.f};
        if (wave < 4) {
            const f16* abase = &A_sm[(q * 16 + r16) * 8];
#pragma unroll
            for (int kk = 0; kk < 24; ++kk) {
                const f16x8 a = *(const f16x8*)(abase + kk * 512);
                if (kk & 1) acc1 = __builtin_amdgcn_mfma_f32_16x16x32_f16(a, bw[kk], acc1, 0, 0, 0);
                else        acc0 = __builtin_amdgcn_mfma_f32_16x16x32_f16(a, bw[kk], acc0, 0, 0, 0);
            }
        } else {
            const f16* abase = &C_sm[(q * 16 + r16) * 8];
#pragma unroll
            for (int kk = 0; kk < 16; ++kk) {
                const f16x8 a = *(const f16x8*)(abase + kk * 512);
                if (kk & 1) acc1 = __builtin_amdgcn_mfma_f32_16x16x32_f16(a, bw[kk], acc1, 0, 0, 0);
                else        acc0 = __builtin_amdgcn_mfma_f32_16x16x32_f16(a, bw[kk], acc0, 0, 0, 0);
            }
        }
        const f32x4 acc = acc0 + acc1;
        // C/D: col = lane&15, row = quad*4 + reg  (row = batch)
#pragma unroll
        for (int r = 0; r < 4; ++r)
            outs_sm[(wave * 16 + q * 4 + r) * 17 + r16] = acc[r];
        __syncthreads();   // B1: outs_sm produced; MFMA done reading A/C_sm

        // ---------- elementwise + tagged publish + wave-local ack ----------
        if (tid < 256) {
            const int b = tid >> 4, jj = tid & 15;
            const int gb = grp * 16 + b;
            const float f  = outs_sm[(0 * 16 + b) * 17 + jj] + bias_sm[0  + jj];
            const float i_ = outs_sm[(1 * 16 + b) * 17 + jj] + bias_sm[16 + jj];
            const float o  = outs_sm[(2 * 16 + b) * 17 + jj] + bias_sm[32 + jj];
            const float ct = outs_sm[(3 * 16 + b) * 17 + jj] + bias_sm[48 + jj];
            const float d  = outs_sm[(4 * 16 + b) * 17 + jj] + bias_sm[64 + jj];
            const float gt = 1.0f / __logf(ECONST + ts);
            const float cs1   = tanh_f(d);
            const float cprev = c_loc[tid];
            const float cadj  = cprev - cs1 + cs1 * gt;
            const float cnew  = sigf(f) * cadj + sigf(i_) * tanh_f(ct);
            const float hnew  = sigf(o) * tanh_f(cnew);
            c_loc[tid] = cnew;
            // publish FIRST — the only vmem op outstanding at the drain
            __hip_atomic_store(hc_g + (size_t)(t & 1) * 8192 + member * 256 + tid,
                               pack_tagged(hnew, cnew, (unsigned int)(t + 1)),
                               __ATOMIC_RELAXED, __HIP_MEMORY_SCOPE_AGENT);
            // own slice straight into LDS operands (lgkm, not on the drain)
            const int col = j0 + jj;
            const int fi = ((col >> 3) * 16 + b) * 8 + (col & 7);
            ((f16*)A_sm)[fi] = (f16)hnew;
            ((f16*)C_sm)[fi] = (f16)cnew;
            // wave-local drain: publish ack'd at MALL => remote publishes
            // (issued ~simultaneously) have already landed there.
            asm volatile("s_waitcnt vmcnt(0)" ::: "memory");
            if ((tid & 63) == 0)
                __hip_atomic_store(&done_sm[wave], (unsigned int)(t + 1),
                                   __ATOMIC_RELAXED, __HIP_MEMORY_SCOPE_WORKGROUP);
            // output stores AFTER the ack signal — off the critical path
            const int len = len_sm[b];
            out0[((size_t)gb * S_ + t) * H_ + col] = (t < len) ? hnew : 0.0f;
            if (t == len - 1) {
                out1[gb * H_ + col] = hnew;
                out2[gb * H_ + col] = cnew;
            }
        }
        asm volatile("" ::: "memory");

        if (t < S_ - 1) {
            // issue x(t+1) loads; latency hides under the gather window
            float4 xv[4];
            if (tid < 256) {
#pragma unroll
                for (int k2 = 0; k2 < 4; ++k2) {
                    const int idx = k2 * 256 + tid;
                    const int b = idx >> 6;
                    const int kx0 = (idx & 63) << 2;
                    xv[k2] = *(const float4*)&inputs[(((size_t)(grp * 16 + b)) * S_ + (t + 1)) * IN_ + kx0];
                }
            }

            // intra-block ack poll: all 4 EW waves' publishes ack'd (~50cy)
            const unsigned int tag = (unsigned int)(t + 1);
            for (;;) {
                unsigned int m = tag;
                if (lane < 4)
                    m = __hip_atomic_load(&done_sm[lane],
                                          __ATOMIC_RELAXED, __HIP_MEMORY_SCOPE_WORKGROUP);
                if (__ballot(m >= tag) == ~0ull) break;
            }
            asm volatile("" ::: "memory");   // gather must not hoist above poll

            // ---------- single-shot gather + sparse retry ----------
            // slice layout: qword j = b*16 + c; lane owns j = 4*lane..+3
            const unsigned long long* src = hc_g + (size_t)(t & 1) * 8192;
            const int jb = lane * 4;
            unsigned long long v[7][4];
            unsigned int pend = (1u << (4 * ns)) - 1u;
            do {
#pragma unroll
                for (int u = 0; u < 7; ++u) {
                    if (u < ns) {
                        const unsigned long long* sb = src + sl[u] * 256 + jb;
#pragma unroll
                        for (int k = 0; k < 4; ++k)
                            if ((pend >> (u * 4 + k)) & 1u)
                                v[u][k] = __hip_atomic_load(sb + k, __ATOMIC_RELAXED,
                                                            __HIP_MEMORY_SCOPE_AGENT);
                    }
                }
#pragma unroll
                for (int u = 0; u < 7; ++u) {
                    if (u < ns) {
#pragma unroll
                        for (int k = 0; k < 4; ++k)
                            if (((pend >> (u * 4 + k)) & 1u) &&
                                (unsigned int)(v[u][k] >> 32) == tag)
                                pend &= ~(1u << (u * 4 + k));
                    }
                }
            } while (__ballot(pend != 0u) != 0ull);

            // unpack: 4 cols per lane per slice -> one uint2 to A_sm + C_sm
            const int ub  = lane >> 2;          // batch row
            const int uc4 = (lane & 3) * 4;     // local col base (0,4,8,12)
#pragma unroll
            for (int u = 0; u < 7; ++u) {
                if (u < ns) {
                    const int s = sl[u];
                    const unsigned int p0 = (unsigned int)v[u][0];
                    const unsigned int p1 = (unsigned int)v[u][1];
                    const unsigned int p2 = (unsigned int)v[u][2];
                    const unsigned int p3 = (unsigned int)v[u][3];
                    const int col = s * 16 + uc4;
                    const int fi  = ((col >> 3) * 16 + ub) * 8 + (col & 7);
                    uint2 hp, cp;
                    hp.x = (p0 & 0xFFFFu) | (p1 << 16);
                    hp.y = (p2 & 0xFFFFu) | (p3 << 16);
                    cp.x = (p0 >> 16) | (p1 & 0xFFFF0000u);
                    cp.y = (p2 >> 16) | (p3 & 0xFFFF0000u);
                    *(uint2*)((f16*)A_sm + fi) = hp;
                    *(uint2*)((f16*)C_sm + fi) = cp;
                }
            }

            // stage x(t+1) into A_sm kb 64..95
            if (tid < 256) {
#pragma unroll
                for (int k2 = 0; k2 < 4; ++k2) {
                    const int idx = k2 * 256 + tid;
                    const int b = idx >> 6;
                    const int kx0 = (idx & 63) << 2;
                    union { f16 h[4]; uint2 u; } p;
                    p.h[0] = (f16)xv[k2].x; p.h[1] = (f16)xv[k2].y;
                    p.h[2] = (f16)xv[k2].z; p.h[3] = (f16)xv[k2].w;
                    const int kb = 64 + (kx0 >> 3), e = kx0 & 7;
                    *(uint2*)&A_sm[(kb * 16 + b) * 8 + e] = p.u;
                }
            }
            __syncthreads();   // B2: operands for step t+1 ready
        }
    }
}

extern "C" void kernel_launch(void* const* d_in, const int* in_sizes, int n_in,
                              void* d_out, int out_size, void* d_ws, size_t ws_size,
                              hipStream_t stream) {
    const float* inputs  = (const float*)d_in[0];
    const float* tstamps = (const float*)d_in[1];
    const int*   lens    = (const int*)d_in[2];
    const float* W_all   = (const float*)d_in[3];
    const float* b_all   = (const float*)d_in[4];
    const float* U_all   = (const float*)d_in[5];
    const float* b_u     = (const float*)d_in[6];
    const float* W_d     = (const float*)d_in[7];
    const float* b_d     = (const float*)d_in[8];

    float* out0 = (float*)d_out;                    // [64,1024,512]
    float* out1 = out0 + (size_t)64 * 1024 * 512;   // last_h [64,512]
    float* out2 = out1 + (size_t)64 * 512;          // last_c [64,512]

    // exchange buffer: 4 groups x 2 phases x 8192 qwords = 512 KB.
    // No memset: tags are compared for EQUALITY with t+1 (<=1024), so the
    // 0xAA..AA poison (hi32 = 0xAAAAAAAA) and stale tags never match.
    unsigned long long* hcbuf = (unsigned long long*)d_ws;

    tlstm_scan<<<dim3(128), dim3(320), 0, stream>>>(
        inputs, tstamps, lens, W_all, b_all, U_all, b_u, W_d, b_d,
        out0, out1, out2, hcbuf);
}

// Round 6
// 3478.622 us; speedup vs baseline: 1.5623x; 1.5623x over previous
//
#include <hip/hip_runtime.h>

// TimeLSTM persistent-scan kernel for MI355X (gfx950), round 9.
// Grid: 128 blocks x 320 threads. grp = blockIdx&3 owns batches grp*16..+15;
// member = blockIdx>>2 owns columns member*16..+15 of each gate and of W_d.
// Weights live in VGPRs as f16 MFMA B-fragments for all 1024 steps.
//
// Round-9 = round-3 protocol VERBATIM (publish -> __syncthreads vmcnt drain ->
// flag -> poll -> single-shot gather; the only structure that doesn't storm —
// R4/R6/R8 all proved consumer loads must never race in-flight publishes),
// plus three ordering-preserving shavings:
//  (1) depth-4 software-pipelined flag poll: 4 same-address relaxed atomic
//      loads in flight -> flag sampled every ~RT/4 instead of every RT
//      (stale samples harmless: monotone flag, >= compare).
//  (2) out0/out1/out2 stores moved AFTER the drain barrier + flag store:
//      the drain now covers only the publish; out write-acks retire under
//      the poll+gather window (>=1.5 RT) before B2 needs them drained.
//  (3) x(t+1) LDS staging moved BEFORE the poll (depends only on xv; the
//      xv wait overlaps flag travel) — shortens the post-gather tail to B2.

typedef _Float16 f16;
typedef _Float16 f16x8 __attribute__((ext_vector_type(8)));
typedef float f32x4 __attribute__((ext_vector_type(4)));

#define S_ 1024
#define IN_ 256
#define H_ 512
#define ECONST 2.718281828459045f

__device__ __forceinline__ float sigf(float x) { return 1.0f / (1.0f + __expf(-x)); }
__device__ __forceinline__ float tanh_f(float x) { return 1.0f - 2.0f / (__expf(2.0f * x) + 1.0f); }

__device__ __forceinline__ unsigned int pack_hc(float h, float c) {
    union { f16 f; unsigned short u; } ph, pc;
    ph.f = (f16)h; pc.f = (f16)c;
    return ((unsigned int)pc.u << 16) | (unsigned int)ph.u;
}

__launch_bounds__(320, 2)
__global__ void tlstm_scan(
    const float* __restrict__ inputs, const float* __restrict__ tstamps,
    const int* __restrict__ lens,
    const float* __restrict__ W_all, const float* __restrict__ b_all,
    const float* __restrict__ U_all, const float* __restrict__ b_u,
    const float* __restrict__ W_d, const float* __restrict__ b_d,
    float* __restrict__ out0, float* __restrict__ out1, float* __restrict__ out2,
    unsigned long long* __restrict__ hcbuf, unsigned int* __restrict__ flags)
{
    __shared__ __align__(16) f16 A_sm[96 * 16 * 8];   // 24 KB  (h: kb0..63, x: kb64..95)
    __shared__ __align__(16) f16 C_sm[64 * 16 * 8];   // 16 KB  (c operand)
    __shared__ float outs_sm[5 * 16 * 17];            // +1 pad on col
    __shared__ float c_loc[16 * 16];                  // fp32 c state (own cells)
    __shared__ float bias_sm[5 * 16];
    __shared__ int   len_sm[16];

    const int tid    = threadIdx.x;
    const int grp    = blockIdx.x & 3;
    const int member = blockIdx.x >> 2;
    const int wave   = tid >> 6;
    const int lane   = tid & 63;
    const int q      = lane >> 4;   // quad
    const int r16    = lane & 15;   // A: m / B: n / C: col
    const int j0     = member * 16;

    // ---------- preload weights into VGPRs as B-fragments ----------
    // B[k][n]: n = lane&15, k = kk*32 + q*8 + e
    f16x8 bw[24];
    if (wave < 4) {
        const int col = wave * 512 + j0 + r16;
#pragma unroll
        for (int kk = 0; kk < 24; ++kk) {
            f16x8 v;
            const int kbase = kk * 32 + q * 8;
#pragma unroll
            for (int e = 0; e < 8; ++e) {
                const int k = kbase + e;
                const float w = (kk < 16) ? W_all[k * 2048 + col]
                                          : U_all[(k - 512) * 2048 + col];
                v[e] = (f16)w;
            }
            bw[kk] = v;
        }
    } else {
        const int col = j0 + r16;
#pragma unroll
        for (int kk = 0; kk < 16; ++kk) {
            f16x8 v;
            const int kbase = kk * 32 + q * 8;
#pragma unroll
            for (int e = 0; e < 8; ++e) v[e] = (f16)W_d[(kbase + e) * 512 + col];
            bw[kk] = v;
        }
#pragma unroll
        for (int kk = 16; kk < 24; ++kk) bw[kk] = bw[0];
    }

    // slice list for this wave (6-7 remote slices, round-robin over 5 waves)
    int sl[7];
    int ns = 0;
    for (int s = wave; s < 32; s += 5)
        if (s != member) sl[ns++] = s;

    // ---------- init LDS state ----------
    {
        uint4 z; z.x = z.y = z.z = z.w = 0u;
        uint4* a4 = (uint4*)A_sm;
        uint4* c4 = (uint4*)C_sm;
        for (int i = tid; i < 1024; i += 320) { a4[i] = z; c4[i] = z; }
        if (tid < 256) c_loc[tid] = 0.0f;
        if (tid < 64) {
            const int w = tid >> 4, n = tid & 15;
            const int col = w * 512 + j0 + n;
            bias_sm[w * 16 + n] = b_all[col] + b_u[col];
        } else if (tid < 80) {
            const int n = tid & 15;
            bias_sm[64 + n] = b_d[j0 + n];
        }
        if (tid < 16) len_sm[tid] = lens[grp * 16 + tid];
        // stage x(0) into A_sm kb 64..95
        for (int idx = tid; idx < 1024; idx += 320) {
            const int b = idx >> 6;
            const int kx0 = (idx & 63) << 2;
            const float4 v = *(const float4*)&inputs[(((size_t)(grp * 16 + b)) * S_ + 0) * IN_ + kx0];
            union { f16 h[4]; uint2 u; } p;
            p.h[0] = (f16)v.x; p.h[1] = (f16)v.y; p.h[2] = (f16)v.z; p.h[3] = (f16)v.w;
            const int kb = 64 + (kx0 >> 3), e = kx0 & 7;
            *(uint2*)&A_sm[(kb * 16 + b) * 8 + e] = p.u;
        }
    }
    __syncthreads();

    // per-group exchange buffer: 2 phases x 4096 qwords (32 KB per phase)
    unsigned long long* const hc_g = hcbuf + (size_t)grp * 2 * 4096;
    unsigned int* const flg = flags + grp * 32;

    for (int t = 0; t < S_; ++t) {
        // ts(t) prefetch — overlaps the MFMA phase below
        float ts = 0.0f;
        if (tid < 256) {
            const int gb = grp * 16 + (tid >> 4);
            ts = tstamps[(size_t)gb * S_ + t];
        }

        // ---------- MFMA phase ----------
        f32x4 acc0 = {0.f, 0.f, 0.f, 0.f}, acc1 = {0.f, 0.f, 0.f, 0.f};
        if (wave < 4) {
            const f16* abase = &A_sm[(q * 16 + r16) * 8];
#pragma unroll
            for (int kk = 0; kk < 24; ++kk) {
                const f16x8 a = *(const f16x8*)(abase + kk * 512);
                if (kk & 1) acc1 = __builtin_amdgcn_mfma_f32_16x16x32_f16(a, bw[kk], acc1, 0, 0, 0);
                else        acc0 = __builtin_amdgcn_mfma_f32_16x16x32_f16(a, bw[kk], acc0, 0, 0, 0);
            }
        } else {
            const f16* abase = &C_sm[(q * 16 + r16) * 8];
#pragma unroll
            for (int kk = 0; kk < 16; ++kk) {
                const f16x8 a = *(const f16x8*)(abase + kk * 512);
                if (kk & 1) acc1 = __builtin_amdgcn_mfma_f32_16x16x32_f16(a, bw[kk], acc1, 0, 0, 0);
                else        acc0 = __builtin_amdgcn_mfma_f32_16x16x32_f16(a, bw[kk], acc0, 0, 0, 0);
            }
        }
        const f32x4 acc = acc0 + acc1;
        // C/D: col = lane&15, row = quad*4 + reg  (row = batch)
#pragma unroll
        for (int r = 0; r < 4; ++r)
            outs_sm[(wave * 16 + q * 4 + r) * 17 + r16] = acc[r];
        __syncthreads();

        // ---------- elementwise gates + publish (out-stores deferred) ----------
        float hnew_r = 0.0f, cnew_r = 0.0f;
        if (tid < 256) {
            const int b = tid >> 4, jj = tid & 15;
            const float f  = outs_sm[(0 * 16 + b) * 17 + jj] + bias_sm[0  + jj];
            const float i_ = outs_sm[(1 * 16 + b) * 17 + jj] + bias_sm[16 + jj];
            const float o  = outs_sm[(2 * 16 + b) * 17 + jj] + bias_sm[32 + jj];
            const float ct = outs_sm[(3 * 16 + b) * 17 + jj] + bias_sm[48 + jj];
            const float d  = outs_sm[(4 * 16 + b) * 17 + jj] + bias_sm[64 + jj];
            const float gt = 1.0f / __logf(ECONST + ts);
            const float cs1   = tanh_f(d);
            const float cprev = c_loc[tid];
            const float cadj  = cprev - cs1 + cs1 * gt;
            const float cnew  = sigf(f) * cadj + sigf(i_) * tanh_f(ct);
            const float hnew  = sigf(o) * tanh_f(cnew);
            c_loc[tid] = cnew;
            hnew_r = hnew; cnew_r = cnew;
            // publish packed (c,h): the ONLY vmem op gating the drain below
            unsigned int* dw = (unsigned int*)(hc_g + (size_t)(t & 1) * 4096);
            __hip_atomic_store(dw + member * 256 + tid, pack_hc(hnew, cnew),
                               __ATOMIC_RELAXED, __HIP_MEMORY_SCOPE_AGENT);
            // own slice straight into LDS operands (never gathered)
            const int col = j0 + jj;
            const int fi = ((col >> 3) * 16 + b) * 8 + (col & 7);
            ((f16*)A_sm)[fi] = (f16)hnew;
            ((f16*)C_sm)[fi] = (f16)cnew;
        }
        __syncthreads();   // drain: publish stores ack'd at MALL (outs excluded)

        const unsigned int tag = (unsigned int)(t + 1);
        if (t < S_ - 1 && tid == 0)
            __hip_atomic_store(&flg[member], tag,
                               __ATOMIC_RELAXED, __HIP_MEMORY_SCOPE_AGENT);

        // output stores AFTER drain + flag — their HBM acks retire under the
        // poll+gather window, never on the critical path
        if (tid < 256) {
            const int b = tid >> 4, jj = tid & 15;
            const int gb = grp * 16 + b;
            const int col = j0 + jj;
            const int len = len_sm[b];
            out0[((size_t)gb * S_ + t) * H_ + col] = (t < len) ? hnew_r : 0.0f;
            if (t == len - 1) {
                out1[gb * H_ + col] = hnew_r;
                out2[gb * H_ + col] = cnew_r;
            }
        }

        if (t < S_ - 1) {
            // issue x(t+1) loads and stage to LDS now — the xv wait overlaps
            // flag travel; staging leaves the post-gather tail
            if (tid < 256) {
                float4 xv[4];
#pragma unroll
                for (int k2 = 0; k2 < 4; ++k2) {
                    const int idx = k2 * 256 + tid;
                    const int b = idx >> 6;
                    const int kx0 = (idx & 63) << 2;
                    xv[k2] = *(const float4*)&inputs[(((size_t)(grp * 16 + b)) * S_ + (t + 1)) * IN_ + kx0];
                }
#pragma unroll
                for (int k2 = 0; k2 < 4; ++k2) {
                    const int idx = k2 * 256 + tid;
                    const int b = idx >> 6;
                    const int kx0 = (idx & 63) << 2;
                    union { f16 h[4]; uint2 u; } p;
                    p.h[0] = (f16)xv[k2].x; p.h[1] = (f16)xv[k2].y;
                    p.h[2] = (f16)xv[k2].z; p.h[3] = (f16)xv[k2].w;
                    const int kb = 64 + (kx0 >> 3), e = kx0 & 7;
                    *(uint2*)&A_sm[(kb * 16 + b) * 8 + e] = p.u;
                }
            }

            // depth-4 pipelined flag poll: sample period ~RT/4; stale samples
            // harmless (monotone flag, >= compare)
            {
                const bool watch = (lane < ns);
                const unsigned int* fp = watch ? &flg[sl[lane]] : &flg[member];
                unsigned int s0 = 0, s1 = 0, s2 = 0, s3 = 0;
                if (watch) {
                    s0 = __hip_atomic_load(fp, __ATOMIC_RELAXED, __HIP_MEMORY_SCOPE_AGENT);
                    s1 = __hip_atomic_load(fp, __ATOMIC_RELAXED, __HIP_MEMORY_SCOPE_AGENT);
                    s2 = __hip_atomic_load(fp, __ATOMIC_RELAXED, __HIP_MEMORY_SCOPE_AGENT);
                    s3 = __hip_atomic_load(fp, __ATOMIC_RELAXED, __HIP_MEMORY_SCOPE_AGENT);
                }
                bool ok = !watch || (s0 >= tag);
                while (__ballot(ok) != ~0ull) {
                    s0 = s1; s1 = s2; s2 = s3;
                    if (!ok)
                        s3 = __hip_atomic_load(fp, __ATOMIC_RELAXED, __HIP_MEMORY_SCOPE_AGENT);
                    ok = ok || (s0 >= tag);
                }
            }
            asm volatile("" ::: "memory");   // gather must not hoist above poll

            // batched gather: 2 qwords per lane per slice, single wait
            const unsigned long long* src = hc_g + (size_t)(t & 1) * 4096;
            unsigned long long v[7][2];
#pragma unroll
            for (int u = 0; u < 7; ++u) {
                if (u < ns) {
                    const int s = sl[u];
                    v[u][0] = __hip_atomic_load(src + s * 128 + lane,
                                                __ATOMIC_RELAXED, __HIP_MEMORY_SCOPE_AGENT);
                    v[u][1] = __hip_atomic_load(src + s * 128 + 64 + lane,
                                                __ATOMIC_RELAXED, __HIP_MEMORY_SCOPE_AGENT);
                }
            }
#pragma unroll
            for (int u = 0; u < 7; ++u) {
                if (u < ns) {
                    const int s = sl[u];
#pragma unroll
                    for (int dd = 0; dd < 2; ++dd) {
                        const int j = dd * 64 + lane;       // qword index in slice
                        const int b = j >> 3;
                        const int colL = (j & 7) * 2;
                        const int col = s * 16 + colL;
                        const unsigned long long qv = v[u][dd];
                        const unsigned int d0 = (unsigned int)qv;
                        const unsigned int d1 = (unsigned int)(qv >> 32);
                        const unsigned int hpair = (d0 & 0xFFFFu) | (d1 << 16);
                        const unsigned int cpair = (d0 >> 16) | (d1 & 0xFFFF0000u);
                        const int fi = ((col >> 3) * 16 + b) * 8 + (col & 7);
                        *(unsigned int*)((f16*)A_sm + fi) = hpair;
                        *(unsigned int*)((f16*)C_sm + fi) = cpair;
                    }
                }
            }
            __syncthreads();   // B2: operands for step t+1 ready
        }
    }
}

extern "C" void kernel_launch(void* const* d_in, const int* in_sizes, int n_in,
                              void* d_out, int out_size, void* d_ws, size_t ws_size,
                              hipStream_t stream) {
    const float* inputs  = (const float*)d_in[0];
    const float* tstamps = (const float*)d_in[1];
    const int*   lens    = (const int*)d_in[2];
    const float* W_all   = (const float*)d_in[3];
    const float* b_all   = (const float*)d_in[4];
    const float* U_all   = (const float*)d_in[5];
    const float* b_u     = (const float*)d_in[6];
    const float* W_d     = (const float*)d_in[7];
    const float* b_d     = (const float*)d_in[8];

    float* out0 = (float*)d_out;                    // [64,1024,512]
    float* out1 = out0 + (size_t)64 * 1024 * 512;   // last_h [64,512]
    float* out2 = out1 + (size_t)64 * 512;          // last_c [64,512]

    char* ws = (char*)d_ws;
    unsigned int* flags = (unsigned int*)ws;                       // 4 grp * 32 dwords
    unsigned long long* hcbuf = (unsigned long long*)(ws + 1024);  // 4 grp * 2 * 32KB = 256KB

    // flags must start at 0 every call (ws is poisoned 0xAA; >= compare)
    hipMemsetAsync(ws, 0, 1024, stream);

    tlstm_scan<<<dim3(128), dim3(320), 0, stream>>>(
        inputs, tstamps, lens, W_all, b_all, U_all, b_u, W_d, b_d,
        out0, out1, out2, hcbuf, flags);
}

// Round 10
// 3470.584 us; speedup vs baseline: 1.5659x; 1.0023x over previous
//
#include <hip/hip_runtime.h>

// TimeLSTM persistent-scan kernel for MI355X (gfx950), round 13 = R9 revert.
// Grid: 128 blocks x 320 threads. grp = blockIdx&3 owns batches grp*16..+15;
// member = blockIdx>>2 owns columns member*16..+15 of each gate and of W_d.
// Weights live in VGPRs as f16 MFMA B-fragments for all 1024 steps.
//
// FINAL STRUCTURE after 10 protocol/topology experiments:
//  - R3 ordering (publish -> block-wide vmcnt drain -> flag -> lane-parallel
//    poll -> single-shot gather) is the ONLY storm-free exchange: R4/R6/R8
//    proved consumer loads racing in-flight publishes congest MALL (+40-75%).
//  - R9 shavings kept (all ordering-preserving): depth-4 pipelined flag poll,
//    out-stores after flag, x-staging before poll. Net +0.5% vs R3 — the
//    chain is raw serialized fabric latency, not detection quantization.
//  - R7 (fewer blocks / wider members): LDS-BW-bound, -10%.
//  - R10/11/12 (same-XCD groups + sc0 L2-scope exchange): hang / silent
//    corruption (sc0 drain-ack is NOT L2-commit-ordered) / hang. Axis dead.
// Remaining step cost ~7.9k cy = ~2k compute + ~5.9k serialized MALL RTs;
// no HIP-source-level mechanism found to shorten the latter.

typedef _Float16 f16;
typedef _Float16 f16x8 __attribute__((ext_vector_type(8)));
typedef float f32x4 __attribute__((ext_vector_type(4)));

#define S_ 1024
#define IN_ 256
#define H_ 512
#define ECONST 2.718281828459045f

__device__ __forceinline__ float sigf(float x) { return 1.0f / (1.0f + __expf(-x)); }
__device__ __forceinline__ float tanh_f(float x) { return 1.0f - 2.0f / (__expf(2.0f * x) + 1.0f); }

__device__ __forceinline__ unsigned int pack_hc(float h, float c) {
    union { f16 f; unsigned short u; } ph, pc;
    ph.f = (f16)h; pc.f = (f16)c;
    return ((unsigned int)pc.u << 16) | (unsigned int)ph.u;
}

__launch_bounds__(320, 2)
__global__ void tlstm_scan(
    const float* __restrict__ inputs, const float* __restrict__ tstamps,
    const int* __restrict__ lens,
    const float* __restrict__ W_all, const float* __restrict__ b_all,
    const float* __restrict__ U_all, const float* __restrict__ b_u,
    const float* __restrict__ W_d, const float* __restrict__ b_d,
    float* __restrict__ out0, float* __restrict__ out1, float* __restrict__ out2,
    unsigned long long* __restrict__ hcbuf, unsigned int* __restrict__ flags)
{
    __shared__ __align__(16) f16 A_sm[96 * 16 * 8];   // 24 KB  (h: kb0..63, x: kb64..95)
    __shared__ __align__(16) f16 C_sm[64 * 16 * 8];   // 16 KB  (c operand)
    __shared__ float outs_sm[5 * 16 * 17];            // +1 pad on col
    __shared__ float c_loc[16 * 16];                  // fp32 c state (own cells)
    __shared__ float bias_sm[5 * 16];
    __shared__ int   len_sm[16];

    const int tid    = threadIdx.x;
    const int grp    = blockIdx.x & 3;
    const int member = blockIdx.x >> 2;
    const int wave   = tid >> 6;
    const int lane   = tid & 63;
    const int q      = lane >> 4;   // quad
    const int r16    = lane & 15;   // A: m / B: n / C: col
    const int j0     = member * 16;

    // ---------- preload weights into VGPRs as B-fragments ----------
    // B[k][n]: n = lane&15, k = kk*32 + q*8 + e
    f16x8 bw[24];
    if (wave < 4) {
        const int col = wave * 512 + j0 + r16;
#pragma unroll
        for (int kk = 0; kk < 24; ++kk) {
            f16x8 v;
            const int kbase = kk * 32 + q * 8;
#pragma unroll
            for (int e = 0; e < 8; ++e) {
                const int k = kbase + e;
                const float w = (kk < 16) ? W_all[k * 2048 + col]
                                          : U_all[(k - 512) * 2048 + col];
                v[e] = (f16)w;
            }
            bw[kk] = v;
        }
    } else {
        const int col = j0 + r16;
#pragma unroll
        for (int kk = 0; kk < 16; ++kk) {
            f16x8 v;
            const int kbase = kk * 32 + q * 8;
#pragma unroll
            for (int e = 0; e < 8; ++e) v[e] = (f16)W_d[(kbase + e) * 512 + col];
            bw[kk] = v;
        }
#pragma unroll
        for (int kk = 16; kk < 24; ++kk) bw[kk] = bw[0];
    }

    // slice list for this wave (6-7 remote slices, round-robin over 5 waves)
    int sl[7];
    int ns = 0;
    for (int s = wave; s < 32; s += 5)
        if (s != member) sl[ns++] = s;

    // ---------- init LDS state ----------
    {
        uint4 z; z.x = z.y = z.z = z.w = 0u;
        uint4* a4 = (uint4*)A_sm;
        uint4* c4 = (uint4*)C_sm;
        for (int i = tid; i < 1024; i += 320) { a4[i] = z; c4[i] = z; }
        if (tid < 256) c_loc[tid] = 0.0f;
        if (tid < 64) {
            const int w = tid >> 4, n = tid & 15;
            const int col = w * 512 + j0 + n;
            bias_sm[w * 16 + n] = b_all[col] + b_u[col];
        } else if (tid < 80) {
            const int n = tid & 15;
            bias_sm[64 + n] = b_d[j0 + n];
        }
        if (tid < 16) len_sm[tid] = lens[grp * 16 + tid];
        // stage x(0) into A_sm kb 64..95
        for (int idx = tid; idx < 1024; idx += 320) {
            const int b = idx >> 6;
            const int kx0 = (idx & 63) << 2;
            const float4 v = *(const float4*)&inputs[(((size_t)(grp * 16 + b)) * S_ + 0) * IN_ + kx0];
            union { f16 h[4]; uint2 u; } p;
            p.h[0] = (f16)v.x; p.h[1] = (f16)v.y; p.h[2] = (f16)v.z; p.h[3] = (f16)v.w;
            const int kb = 64 + (kx0 >> 3), e = kx0 & 7;
            *(uint2*)&A_sm[(kb * 16 + b) * 8 + e] = p.u;
        }
    }
    __syncthreads();

    // per-group exchange buffer: 2 phases x 4096 qwords (32 KB per phase)
    unsigned long long* const hc_g = hcbuf + (size_t)grp * 2 * 4096;
    unsigned int* const flg = flags + grp * 32;

    for (int t = 0; t < S_; ++t) {
        // ts(t) prefetch — overlaps the MFMA phase below
        float ts = 0.0f;
        if (tid < 256) {
            const int gb = grp * 16 + (tid >> 4);
            ts = tstamps[(size_t)gb * S_ + t];
        }

        // ---------- MFMA phase ----------
        f32x4 acc0 = {0.f, 0.f, 0.f, 0.f}, acc1 = {0.f, 0.f, 0.f, 0.f};
        if (wave < 4) {
            const f16* abase = &A_sm[(q * 16 + r16) * 8];
#pragma unroll
            for (int kk = 0; kk < 24; ++kk) {
                const f16x8 a = *(const f16x8*)(abase + kk * 512);
                if (kk & 1) acc1 = __builtin_amdgcn_mfma_f32_16x16x32_f16(a, bw[kk], acc1, 0, 0, 0);
                else        acc0 = __builtin_amdgcn_mfma_f32_16x16x32_f16(a, bw[kk], acc0, 0, 0, 0);
            }
        } else {
            const f16* abase = &C_sm[(q * 16 + r16) * 8];
#pragma unroll
            for (int kk = 0; kk < 16; ++kk) {
                const f16x8 a = *(const f16x8*)(abase + kk * 512);
                if (kk & 1) acc1 = __builtin_amdgcn_mfma_f32_16x16x32_f16(a, bw[kk], acc1, 0, 0, 0);
                else        acc0 = __builtin_amdgcn_mfma_f32_16x16x32_f16(a, bw[kk], acc0, 0, 0, 0);
            }
        }
        const f32x4 acc = acc0 + acc1;
        // C/D: col = lane&15, row = quad*4 + reg  (row = batch)
#pragma unroll
        for (int r = 0; r < 4; ++r)
            outs_sm[(wave * 16 + q * 4 + r) * 17 + r16] = acc[r];
        __syncthreads();

        // ---------- elementwise gates + publish (out-stores deferred) ----------
        float hnew_r = 0.0f, cnew_r = 0.0f;
        if (tid < 256) {
            const int b = tid >> 4, jj = tid & 15;
            const float f  = outs_sm[(0 * 16 + b) * 17 + jj] + bias_sm[0  + jj];
            const float i_ = outs_sm[(1 * 16 + b) * 17 + jj] + bias_sm[16 + jj];
            const float o  = outs_sm[(2 * 16 + b) * 17 + jj] + bias_sm[32 + jj];
            const float ct = outs_sm[(3 * 16 + b) * 17 + jj] + bias_sm[48 + jj];
            const float d  = outs_sm[(4 * 16 + b) * 17 + jj] + bias_sm[64 + jj];
            const float gt = 1.0f / __logf(ECONST + ts);
            const float cs1   = tanh_f(d);
            const float cprev = c_loc[tid];
            const float cadj  = cprev - cs1 + cs1 * gt;
            const float cnew  = sigf(f) * cadj + sigf(i_) * tanh_f(ct);
            const float hnew  = sigf(o) * tanh_f(cnew);
            c_loc[tid] = cnew;
            hnew_r = hnew; cnew_r = cnew;
            // publish packed (c,h): the ONLY vmem op gating the drain below
            unsigned int* dw = (unsigned int*)(hc_g + (size_t)(t & 1) * 4096);
            __hip_atomic_store(dw + member * 256 + tid, pack_hc(hnew, cnew),
                               __ATOMIC_RELAXED, __HIP_MEMORY_SCOPE_AGENT);
            // own slice straight into LDS operands (never gathered)
            const int col = j0 + jj;
            const int fi = ((col >> 3) * 16 + b) * 8 + (col & 7);
            ((f16*)A_sm)[fi] = (f16)hnew;
            ((f16*)C_sm)[fi] = (f16)cnew;
        }
        __syncthreads();   // drain: publish stores ack'd at MALL (outs excluded)

        const unsigned int tag = (unsigned int)(t + 1);
        if (t < S_ - 1 && tid == 0)
            __hip_atomic_store(&flg[member], tag,
                               __ATOMIC_RELAXED, __HIP_MEMORY_SCOPE_AGENT);

        // output stores AFTER drain + flag — their HBM acks retire under the
        // poll+gather window, never on the critical path
        if (tid < 256) {
            const int b = tid >> 4, jj = tid & 15;
            const int gb = grp * 16 + b;
            const int col = j0 + jj;
            const int len = len_sm[b];
            out0[((size_t)gb * S_ + t) * H_ + col] = (t < len) ? hnew_r : 0.0f;
            if (t == len - 1) {
                out1[gb * H_ + col] = hnew_r;
                out2[gb * H_ + col] = cnew_r;
            }
        }

        if (t < S_ - 1) {
            // issue x(t+1) loads and stage to LDS now — the xv wait overlaps
            // flag travel; staging leaves the post-gather tail
            if (tid < 256) {
                float4 xv[4];
#pragma unroll
                for (int k2 = 0; k2 < 4; ++k2) {
                    const int idx = k2 * 256 + tid;
                    const int b = idx >> 6;
                    const int kx0 = (idx & 63) << 2;
                    xv[k2] = *(const float4*)&inputs[(((size_t)(grp * 16 + b)) * S_ + (t + 1)) * IN_ + kx0];
                }
#pragma unroll
                for (int k2 = 0; k2 < 4; ++k2) {
                    const int idx = k2 * 256 + tid;
                    const int b = idx >> 6;
                    const int kx0 = (idx & 63) << 2;
                    union { f16 h[4]; uint2 u; } p;
                    p.h[0] = (f16)xv[k2].x; p.h[1] = (f16)xv[k2].y;
                    p.h[2] = (f16)xv[k2].z; p.h[3] = (f16)xv[k2].w;
                    const int kb = 64 + (kx0 >> 3), e = kx0 & 7;
                    *(uint2*)&A_sm[(kb * 16 + b) * 8 + e] = p.u;
                }
            }

            // depth-4 pipelined flag poll: sample period ~RT/4; stale samples
            // harmless (monotone flag, >= compare)
            {
                const bool watch = (lane < ns);
                const unsigned int* fp = watch ? &flg[sl[lane]] : &flg[member];
                unsigned int s0 = 0, s1 = 0, s2 = 0, s3 = 0;
                if (watch) {
                    s0 = __hip_atomic_load(fp, __ATOMIC_RELAXED, __HIP_MEMORY_SCOPE_AGENT);
                    s1 = __hip_atomic_load(fp, __ATOMIC_RELAXED, __HIP_MEMORY_SCOPE_AGENT);
                    s2 = __hip_atomic_load(fp, __ATOMIC_RELAXED, __HIP_MEMORY_SCOPE_AGENT);
                    s3 = __hip_atomic_load(fp, __ATOMIC_RELAXED, __HIP_MEMORY_SCOPE_AGENT);
                }
                bool ok = !watch || (s0 >= tag);
                while (__ballot(ok) != ~0ull) {
                    s0 = s1; s1 = s2; s2 = s3;
                    if (!ok)
                        s3 = __hip_atomic_load(fp, __ATOMIC_RELAXED, __HIP_MEMORY_SCOPE_AGENT);
                    ok = ok || (s0 >= tag);
                }
            }
            asm volatile("" ::: "memory");   // gather must not hoist above poll

            // batched gather: 2 qwords per lane per slice, single wait
            const unsigned long long* src = hc_g + (size_t)(t & 1) * 4096;
            unsigned long long v[7][2];
#pragma unroll
            for (int u = 0; u < 7; ++u) {
                if (u < ns) {
                    const int s = sl[u];
                    v[u][0] = __hip_atomic_load(src + s * 128 + lane,
                                                __ATOMIC_RELAXED, __HIP_MEMORY_SCOPE_AGENT);
                    v[u][1] = __hip_atomic_load(src + s * 128 + 64 + lane,
                                                __ATOMIC_RELAXED, __HIP_MEMORY_SCOPE_AGENT);
                }
            }
#pragma unroll
            for (int u = 0; u < 7; ++u) {
                if (u < ns) {
                    const int s = sl[u];
#pragma unroll
                    for (int dd = 0; dd < 2; ++dd) {
                        const int j = dd * 64 + lane;       // qword index in slice
                        const int b = j >> 3;
                        const int colL = (j & 7) * 2;
                        const int col = s * 16 + colL;
                        const unsigned long long qv = v[u][dd];
                        const unsigned int d0 = (unsigned int)qv;
                        const unsigned int d1 = (unsigned int)(qv >> 32);
                        const unsigned int hpair = (d0 & 0xFFFFu) | (d1 << 16);
                        const unsigned int cpair = (d0 >> 16) | (d1 & 0xFFFF0000u);
                        const int fi = ((col >> 3) * 16 + b) * 8 + (col & 7);
                        *(unsigned int*)((f16*)A_sm + fi) = hpair;
                        *(unsigned int*)((f16*)C_sm + fi) = cpair;
                    }
                }
            }
            __syncthreads();   // B2: operands for step t+1 ready
        }
    }
}

extern "C" void kernel_launch(void* const* d_in, const int* in_sizes, int n_in,
                              void* d_out, int out_size, void* d_ws, size_t ws_size,
                              hipStream_t stream) {
    const float* inputs  = (const float*)d_in[0];
    const float* tstamps = (const float*)d_in[1];
    const int*   lens    = (const int*)d_in[2];
    const float* W_all   = (const float*)d_in[3];
    const float* b_all   = (const float*)d_in[4];
    const float* U_all   = (const float*)d_in[5];
    const float* b_u     = (const float*)d_in[6];
    const float* W_d     = (const float*)d_in[7];
    const float* b_d     = (const float*)d_in[8];

    float* out0 = (float*)d_out;                    // [64,1024,512]
    float* out1 = out0 + (size_t)64 * 1024 * 512;   // last_h [64,512]
    float* out2 = out1 + (size_t)64 * 512;          // last_c [64,512]

    char* ws = (char*)d_ws;
    unsigned int* flags = (unsigned int*)ws;                       // 4 grp * 32 dwords
    unsigned long long* hcbuf = (unsigned long long*)(ws + 1024);  // 4 grp * 2 * 32KB = 256KB

    // flags must start at 0 every call (ws is poisoned 0xAA; >= compare)
    hipMemsetAsync(ws, 0, 1024, stream);

    tlstm_scan<<<dim3(128), dim3(320), 0, stream>>>(
        inputs, tstamps, lens, W_all, b_all, U_all, b_u, W_d, b_d,
        out0, out1, out2, hcbuf, flags);
}